// Round 2
// baseline (296.028 us; speedup 1.0000x reference)
//
#include <hip/hip_runtime.h>
#include <math.h>

#define BINS 30

static constexpr int BLOCK  = 256;
static constexpr int GRID   = 1024;  // 4 resident blocks/CU (33 KiB LDS) x 256 CUs
static constexpr int SLOTS  = 32;    // 30 bins + slot 30 = trash (out-of-range), 31 pad
static constexpr int UNROLL = 8;     // float4 loads per array per superiteration (16 KiB/wave in flight)

typedef float f32x4 __attribute__((ext_vector_type(4)));  // native vec: OK for nontemporal builtins

__device__ __forceinline__ float wave_sum(float v) {
    #pragma unroll
    for (int o = 32; o > 0; o >>= 1) v += __shfl_xor(v, o, 64);
    return v;
}

// Per-thread private packed histograms in LDS: h[slot*256 + tid] holds
// x-count in bits 0..15 (+1), y-count in bits 16..31 (+65536).
// ds_add_u32 fire-and-forget; bank = tid%32 (2-way within wave = free).
//
// R6 = R4 geometry (R1's occupancy bump was refuted: latency-hiding needs
// only ~9 KiB in flight/CU; we had 128 KiB) with two changes:
//  1. UNROLL 4->8: 16 independent dwordx4 in flight per wave between
//     vmcnt drains (halves the per-superiteration ~900-cyc NT bubble count
//     -- the same lever that was the prior session's biggest win at 2K->8K).
//  2. finalize fused via last-block ticket (device atomics), removing one
//     kernel launch + graph gap. Ticket word = g_hist[63], zeroed by the
//     same 64-u32 memset.
// Exactness: per-thread per-slot x-count <= 2^25/(1024*256) = 128 < 2^16;
// per-block per-slot column sum <= 32768 < 2^16 -> packed u32 sums exact.
__global__ __launch_bounds__(BLOCK, 4) void hist_kernel(
        const float* __restrict__ x, const float* __restrict__ y,
        int n4, unsigned int* __restrict__ g_hist, float* __restrict__ out)
{
    __shared__ unsigned int h[SLOTS * BLOCK];     // 32 KiB
    __shared__ unsigned int partial[BLOCK];       // +1 KiB
    __shared__ unsigned int is_last;
    const int tid = threadIdx.x;

    #pragma unroll
    for (int i = 0; i < SLOTS; ++i) h[i * BLOCK + tid] = 0u;
    __syncthreads();

    const f32x4* __restrict__ x4 = (const f32x4*)x;
    const f32x4* __restrict__ y4 = (const f32x4*)y;

    // torch.histc: idx = floor((v+4)*3.75) clipped to [0,29]; |v|>4 (or NaN) -> trash slot 30
    #define PROC(v, inc) {                                              \
        float q = fmaf((v), 3.75f, 15.0f);                              \
        int idx = (int)q;                                               \
        idx = idx > 29 ? 29 : idx;        /* v == 4.0 -> last bin */    \
        bool valid = fabsf(v) <= 4.0f;                                  \
        int slot = valid ? idx : 30;                                    \
        atomicAdd(&h[slot * BLOCK + tid], (inc));  /* ds_add_u32 */     \
    }
    #define PROC4(f, inc) { PROC((f).x, inc) PROC((f).y, inc) PROC((f).z, inc) PROC((f).w, inc) }

    const int span   = GRID * BLOCK * UNROLL;      // float4 per superiteration
    const int chunk0 = blockIdx.x * (BLOCK * UNROLL);

    for (int chunk = chunk0; chunk + BLOCK * UNROLL <= n4; chunk += span) {
        f32x4 a[UNROLL], b[UNROLL];
        #pragma unroll
        for (int j = 0; j < UNROLL; ++j)
            a[j] = __builtin_nontemporal_load(&x4[chunk + j * BLOCK + tid]);
        #pragma unroll
        for (int j = 0; j < UNROLL; ++j)
            b[j] = __builtin_nontemporal_load(&y4[chunk + j * BLOCK + tid]);
        #pragma unroll
        for (int j = 0; j < UNROLL; ++j) {
            PROC4(a[j], 1u)
            PROC4(b[j], 65536u)
        }
    }

    // Tail (empty for the benchmark's 2^23 float4s; kept for generality)
    const int tail_start = n4 - (n4 % span);
    for (int i = tail_start + blockIdx.x * BLOCK + tid; i < n4; i += GRID * BLOCK) {
        f32x4 a = x4[i], b = y4[i];
        PROC4(a, 1u)
        PROC4(b, 65536u)
    }
    #undef PROC4
    #undef PROC
    __syncthreads();

    // Reduce 256 columns per slot (packed u32 sums exact).
    const int slot = tid & 31;
    const int c0   = (tid >> 5) * 32;
    unsigned int s = 0;
    #pragma unroll 8
    for (int c = 0; c < 32; ++c) {
        int col = c0 + ((c + tid) & 31);
        s += h[slot * BLOCK + col];
    }
    partial[tid] = s;
    __syncthreads();
    if (tid < 32) {
        unsigned int tot = 0;
        #pragma unroll
        for (int g = 0; g < 8; ++g) tot += partial[g * 32 + tid];
        if (tid < BINS) {
            atomicAdd(&g_hist[tid],      tot & 0xFFFFu);  // x histogram
            atomicAdd(&g_hist[32 + tid], tot >> 16);      // y histogram
        }
        __threadfence();   // order this thread's g_hist atomics before the ticket
    }
    __syncthreads();       // vmcnt(0) drain: block's global atomics complete

    // Last-done block computes the MI scalar (replaces the finalize kernel).
    if (tid == 0) {
        unsigned int t = atomicAdd(&g_hist[63], 1u);   // ticket, zeroed by memset
        is_last = (t == GRID - 1) ? 1u : 0u;
    }
    __syncthreads();
    if (is_last && tid < 64) {
        const int t = tid;
        const bool active = t < BINS;
        // Coherent reads (atomic-with-return) -- other XCDs' L2 updates visible.
        float hx = active ? (float)atomicAdd(&g_hist[t],      0u) : 0.0f;
        float hy = active ? (float)atomicAdd(&g_hist[32 + t], 0u) : 0.0f;
        float hj = hx + hy;                      // joint = hist_x + hist_y exactly

        float Sx = wave_sum(hx);
        float Sy = wave_sum(hy);
        float Sj = wave_sum(hj);

        float px = hx / Sx;
        float py = hy / Sy;
        float jp = hj / Sj;

        // mi = 30 * sum_j jp_j*(log jp_j - log py_j) - (sum_j jp_j) * (sum_i log px_i)
        float term = active ? jp * (logf(jp) - logf(py)) : 0.0f;
        float lpx  = active ? logf(px) : 0.0f;
        float sjp  = wave_sum(active ? jp : 0.0f);

        float st = wave_sum(term);
        float sl = wave_sum(lpx);
        if (t == 0) out[0] = -((float)BINS * st - sjp * sl);
    }
}

extern "C" void kernel_launch(void* const* d_in, const int* in_sizes, int n_in,
                              void* d_out, int out_size, void* d_ws, size_t ws_size,
                              hipStream_t stream) {
    const float* x = (const float*)d_in[0];
    const float* y = (const float*)d_in[1];
    const int n = in_sizes[0];               // 2^25, divisible by 4
    unsigned int* g_hist = (unsigned int*)d_ws;

    (void)hipMemsetAsync(d_ws, 0, 64 * sizeof(unsigned int), stream);  // ws is poisoned 0xAA
    hist_kernel<<<GRID, BLOCK, 0, stream>>>(x, y, n >> 2, g_hist, (float*)d_out);
}

// Round 3
// 258.595 us; speedup vs baseline: 1.1448x; 1.1448x over previous
//
#include <hip/hip_runtime.h>
#include <math.h>

#define BINS 30

static constexpr int BLOCK  = 256;
static constexpr int GRID   = 1024;  // 4 resident blocks/CU (33 KiB LDS) x 256 CUs
static constexpr int SLOTS  = 32;    // 30 bins + slot 30 = trash (out-of-range), 31 pad
static constexpr int UNROLL = 4;     // float4 loads per array per chunk (8 KiB/wave per burst)

typedef float f32x4 __attribute__((ext_vector_type(4)));  // native vec: OK for nontemporal builtins

__device__ __forceinline__ float wave_sum(float v) {
    #pragma unroll
    for (int o = 32; o > 0; o >>= 1) v += __shfl_xor(v, o, 64);
    return v;
}

// Per-thread private packed histograms in LDS: h[slot*256 + tid] holds
// x-count in bits 0..15 (+1), y-count in bits 16..31 (+65536).
// ds_add_u32 fire-and-forget; columns are thread-private (tid), bank =
// tid%32, 2-way within wave = free (m136). SQ_LDS_BANK_CONFLICT = 0 verified.
//
// R7 post-mortem of R2: UNROLL=8 regressed (VGPR squeezed to 64 -> the
// 16-load burst couldn't stay in flight) and the fused-finalize threadfence
// added per-block cost. Reverted both to the proven R0 geometry.
// New lever: REGISTER DOUBLE-BUFFER. R0's structure was burst(8 loads) ->
// full drain -> consume; counters showed ~0 loads in flight during consume
// (effective 2.9 TB/s, all pipes idle). Here the next chunk's 8 loads are
// issued BEFORE consuming the current chunk (static ping-pong names, no
// runtime indexing -> no scratch), so the compiler emits a counted
// s_waitcnt vmcnt(8) and loads overlap every consume phase.
// VGPRs: 64 data + ~25 misc < 128 cap at launch_bounds(256,4) -> no spill.
// Exactness: per-thread per-slot x-count <= 128 < 2^16; per-block per-slot
// column sum <= 32768 < 2^16 -> packed u32 sums exact.
__global__ __launch_bounds__(BLOCK, 4) void hist_kernel(
        const float* __restrict__ x, const float* __restrict__ y,
        int n4, unsigned int* __restrict__ g_hist)
{
    __shared__ unsigned int h[SLOTS * BLOCK];     // 32 KiB
    __shared__ unsigned int partial[BLOCK];       // +1 KiB
    const int tid = threadIdx.x;

    #pragma unroll
    for (int i = 0; i < SLOTS; ++i) h[i * BLOCK + tid] = 0u;
    __syncthreads();

    const f32x4* __restrict__ x4 = (const f32x4*)x;
    const f32x4* __restrict__ y4 = (const f32x4*)y;

    // torch.histc: idx = floor((v+4)*3.75) clipped to [0,29]; |v|>4 (or NaN) -> trash slot 30
    #define PROC(v, inc) {                                              \
        float q = fmaf((v), 3.75f, 15.0f);                              \
        int idx = (int)q;                                               \
        idx = idx > 29 ? 29 : idx;        /* v == 4.0 -> last bin */    \
        bool valid = fabsf(v) <= 4.0f;                                  \
        int slot = valid ? idx : 30;                                    \
        atomicAdd(&h[slot * BLOCK + tid], (inc));  /* ds_add_u32 */     \
    }
    #define PROC4(f, inc) { PROC((f).x, inc) PROC((f).y, inc) PROC((f).z, inc) PROC((f).w, inc) }

    // Ping-pong register buffers -- names static, never runtime-indexed.
    f32x4 aA[UNROLL], bA[UNROLL], aB[UNROLL], bB[UNROLL];

    #define LOAD(S, c) {                                                     \
        _Pragma("unroll")                                                    \
        for (int j = 0; j < UNROLL; ++j) {                                   \
            a##S[j] = __builtin_nontemporal_load(&x4[(c) + j * BLOCK + tid]);\
            b##S[j] = __builtin_nontemporal_load(&y4[(c) + j * BLOCK + tid]);\
        } }
    #define CONSUME(S) {                                                     \
        _Pragma("unroll")                                                    \
        for (int j = 0; j < UNROLL; ++j) {                                   \
            PROC4(a##S[j], 1u)                                               \
            PROC4(b##S[j], 65536u)                                           \
        } }

    const int span    = GRID * BLOCK * UNROLL;   // float4 stride per chunk step
    const int iter_sz = BLOCK * UNROLL;
    int cA = blockIdx.x * iter_sz;

    if (cA + iter_sz <= n4) {
        LOAD(A, cA)
        for (;;) {
            const int cB = cA + span;
            const bool hasB = (cB + iter_sz <= n4);
            if (hasB) LOAD(B, cB)          // 8 loads in flight over CONSUME(A)
            CONSUME(A)
            if (!hasB) break;
            const int cN = cB + span;
            const bool hasA = (cN + iter_sz <= n4);
            if (hasA) LOAD(A, cN)          // 8 loads in flight over CONSUME(B)
            CONSUME(B)
            if (!hasA) break;
            cA = cN;
        }
    }

    // Tail (empty for the benchmark's 2^23 float4s; kept for generality)
    const int tail_start = n4 - (n4 % iter_sz ? n4 % iter_sz : 0);
    for (int i = (n4 / iter_sz) * iter_sz + blockIdx.x * BLOCK + tid; i < n4; i += GRID * BLOCK) {
        f32x4 a = x4[i], b = y4[i];
        PROC4(a, 1u)
        PROC4(b, 65536u)
    }
    (void)tail_start;
    #undef CONSUME
    #undef LOAD
    #undef PROC4
    #undef PROC
    __syncthreads();

    // Reduce 256 columns per slot (packed u32 sums exact).
    const int slot = tid & 31;
    const int c0   = (tid >> 5) * 32;
    unsigned int s = 0;
    #pragma unroll 8
    for (int c = 0; c < 32; ++c) {
        int col = c0 + ((c + tid) & 31);
        s += h[slot * BLOCK + col];
    }
    partial[tid] = s;
    __syncthreads();
    if (tid < 32) {
        unsigned int tot = 0;
        #pragma unroll
        for (int g = 0; g < 8; ++g) tot += partial[g * 32 + tid];
        if (tid < BINS) {
            atomicAdd(&g_hist[tid],      tot & 0xFFFFu);  // x histogram
            atomicAdd(&g_hist[32 + tid], tot >> 16);      // y histogram
        }
    }
}

__global__ void finalize_kernel(const unsigned int* __restrict__ g_hist,
                                float* __restrict__ out)
{
    const int t = threadIdx.x;
    const bool active = t < BINS;
    float hx = active ? (float)g_hist[t]      : 0.0f;
    float hy = active ? (float)g_hist[32 + t] : 0.0f;
    float hj = hx + hy;                      // joint = hist_x + hist_y exactly

    float Sx = wave_sum(hx);
    float Sy = wave_sum(hy);
    float Sj = wave_sum(hj);

    float px = hx / Sx;
    float py = hy / Sy;
    float jp = hj / Sj;

    // mi = 30 * sum_j jp_j*(log jp_j - log py_j) - (sum_j jp_j) * (sum_i log px_i)
    float term = active ? jp * (logf(jp) - logf(py)) : 0.0f;
    float lpx  = active ? logf(px) : 0.0f;
    float sjp  = wave_sum(active ? jp : 0.0f);

    float st = wave_sum(term);
    float sl = wave_sum(lpx);
    if (t == 0) out[0] = -((float)BINS * st - sjp * sl);
}

extern "C" void kernel_launch(void* const* d_in, const int* in_sizes, int n_in,
                              void* d_out, int out_size, void* d_ws, size_t ws_size,
                              hipStream_t stream) {
    const float* x = (const float*)d_in[0];
    const float* y = (const float*)d_in[1];
    const int n = in_sizes[0];               // 2^25, divisible by 4
    unsigned int* g_hist = (unsigned int*)d_ws;

    (void)hipMemsetAsync(d_ws, 0, 64 * sizeof(unsigned int), stream);  // ws is poisoned 0xAA
    hist_kernel<<<GRID, BLOCK, 0, stream>>>(x, y, n >> 2, g_hist);
    finalize_kernel<<<1, 64, 0, stream>>>(g_hist, (float*)d_out);
}